// Round 5
// baseline (550.992 us; speedup 1.0000x reference)
//
#include <hip/hip_runtime.h>
#include <stdint.h>

// B=4, S=2048, D=1024, H=16, DK=64. fp32 in/out, bf16 MFMA internal.
// Pipeline (ws = 58.7 MB):
//   0) cvt_w: Wq,Wk,Wv,Wp fp32 -> bf16
//   1) gemm_qkv (z=0,1,2): Q,K -> bf16 [8192][1024] (Q pre-scaled by
//      0.125*log2e); V -> Vt[(b,h,dk)][s] bf16. A fp32 staged w/ fused
//      fast-cvt + prefetch; W via async global_load_lds.
//   2) attn v2: flash causal, Q-tile 128, NO barriers in K-loop — K/V MFMA
//      B-fragments loaded directly from global (L1-resident tiles), LDS only
//      for the wave-private P transpose strip. Per-wave causal loop bounds.
//      Output in place into Qb.
//   3) gemm_proj: pure-bf16 async-staged -> fp32 d_out.

#define SZB (8192u * 1024u * 2u)   // one [8192][1024] bf16 buffer
#define WSZ (1024u * 1024u * 2u)   // one [1024][1024] bf16 weight

typedef __attribute__((ext_vector_type(8))) short  short8;
typedef __attribute__((ext_vector_type(4))) float  f32x4;

#define MFMA16(a, b, c) __builtin_amdgcn_mfma_f32_16x16x32_bf16(a, b, c, 0, 0, 0)

__device__ __forceinline__ ushort f2bf(float f) {        // RNE (epilogues)
  uint32_t u = __float_as_uint(f);
  u += 0x7FFF + ((u >> 16) & 1);
  return (ushort)(u >> 16);
}
__device__ __forceinline__ ushort f2bf_fast(float f) {   // round-half-up, 2 VALU
  return (ushort)((__float_as_uint(f) + 0x8000u) >> 16);
}
__device__ __forceinline__ short8 cvt8(float4 a, float4 b) {  // hot staging path
  short8 r;
  r[0] = (short)f2bf_fast(a.x); r[1] = (short)f2bf_fast(a.y);
  r[2] = (short)f2bf_fast(a.z); r[3] = (short)f2bf_fast(a.w);
  r[4] = (short)f2bf_fast(b.x); r[5] = (short)f2bf_fast(b.y);
  r[6] = (short)f2bf_fast(b.z); r[7] = (short)f2bf_fast(b.w);
  return r;
}
__device__ __forceinline__ void gl_lds16(const ushort* g, ushort* l) {
  __builtin_amdgcn_global_load_lds(
      (__attribute__((address_space(1))) void*)g,
      (__attribute__((address_space(3))) void*)l, 16, 0, 0);
}

// ---------------------------------------------------------------------------
// Weight conversion: 4 x [1024][1024] fp32 -> bf16. grid (512, 4).
// ---------------------------------------------------------------------------
__global__ __launch_bounds__(256) void cvt_w(
    const float* __restrict__ Wq, const float* __restrict__ Wk,
    const float* __restrict__ Wv, const float* __restrict__ Wp,
    ushort* __restrict__ Wqb, ushort* __restrict__ Wkb,
    ushort* __restrict__ Wvb, ushort* __restrict__ Wpb) {
  const int z = blockIdx.y;
  const float* s = (z == 0) ? Wq : (z == 1) ? Wk : (z == 2) ? Wv : Wp;
  ushort* d = (z == 0) ? Wqb : (z == 1) ? Wkb : (z == 2) ? Wvb : Wpb;
  const size_t i = (size_t)(blockIdx.x * 256 + threadIdx.x) * 8;
  *(short8*)&d[i] = cvt8(*(const float4*)&s[i], *(const float4*)&s[i + 4]);
}

// ---------------------------------------------------------------------------
// Mixed core: C = A[M,K]fp32 * W[N,K]bf16^T. 128x128 tile, BK=32.
// ---------------------------------------------------------------------------
__device__ __forceinline__ void gemm_core_mixed(
    const float* __restrict__ A, const ushort* __restrict__ Wb,
    ushort* As, ushort* Bs, int m0, int n0, f32x4 acc[4][4]) {
  const int tid  = threadIdx.x;
  const int w    = tid >> 6;
  const int lane = tid & 63;
  const int quad = lane >> 4;
  const int l16  = lane & 15;
  const int wm   = (w >> 1) * 64;
  const int wn   = (w & 1) * 64;
  const int r0   = tid >> 2;
  const int r1   = r0 + 64;
  const int c0   = (tid & 3) * 8;

  const ushort* Wg = Wb + (size_t)(n0 + w * 32 + (lane >> 2)) * 1024 + (lane & 3) * 8;
  const float*  Ag0 = A + (size_t)(m0 + r0) * 1024 + c0;
  const float*  Ag1 = A + (size_t)(m0 + r1) * 1024 + c0;

  float4 p0a = *(const float4*)(Ag0), p0b = *(const float4*)(Ag0 + 4);
  float4 p1a = *(const float4*)(Ag1), p1b = *(const float4*)(Ag1 + 4);

  for (int kt = 0; kt < 32; ++kt) {
    const int ko = kt * 32;
    __syncthreads();   // prior iteration's LDS readers done
    *(short8*)&As[r0 * 32 + c0] = cvt8(p0a, p0b);
    *(short8*)&As[r1 * 32 + c0] = cvt8(p1a, p1b);
    gl_lds16(Wg + ko,         &Bs[(w * 32) * 32]);
    gl_lds16(Wg + 16384 + ko, &Bs[(w * 32 + 16) * 32]);
    __syncthreads();   // staging visible
    if (kt < 31) {     // prefetch next A chunk; latency hides under MFMA
      const int kn = ko + 32;
      p0a = *(const float4*)(Ag0 + kn); p0b = *(const float4*)(Ag0 + kn + 4);
      p1a = *(const float4*)(Ag1 + kn); p1b = *(const float4*)(Ag1 + kn + 4);
    }
    short8 af[4], bfr[4];
#pragma unroll
    for (int i = 0; i < 4; ++i)
      af[i] = *(const short8*)&As[(wm + i * 16 + l16) * 32 + quad * 8];
#pragma unroll
    for (int i = 0; i < 4; ++i)
      bfr[i] = *(const short8*)&Bs[(wn + i * 16 + l16) * 32 + quad * 8];
#pragma unroll
    for (int i = 0; i < 4; ++i)
#pragma unroll
      for (int j = 0; j < 4; ++j)
        acc[i][j] = MFMA16(af[i], bfr[j], acc[i][j]);
  }
}

// ---------------------------------------------------------------------------
// Pure-bf16 core (m97 structure).
// ---------------------------------------------------------------------------
__device__ __forceinline__ void gemm_core_bf(
    const ushort* __restrict__ A, const ushort* __restrict__ Wb,
    ushort* As, ushort* Bs, int m0, int n0, f32x4 acc[4][4]) {
  const int tid  = threadIdx.x;
  const int w    = tid >> 6;
  const int lane = tid & 63;
  const int quad = lane >> 4;
  const int l16  = lane & 15;
  const int wm   = (w >> 1) * 64;
  const int wn   = (w & 1) * 64;

  const ushort* Ag = A + (size_t)(m0 + w * 32 + (lane >> 2)) * 1024 + (lane & 3) * 8;
  const ushort* Wg = Wb + (size_t)(n0 + w * 32 + (lane >> 2)) * 1024 + (lane & 3) * 8;

  for (int kt = 0; kt < 32; ++kt) {
    const int ko = kt * 32;
    gl_lds16(Ag + ko,         &As[(w * 32) * 32]);
    gl_lds16(Ag + 16384 + ko, &As[(w * 32 + 16) * 32]);
    gl_lds16(Wg + ko,         &Bs[(w * 32) * 32]);
    gl_lds16(Wg + 16384 + ko, &Bs[(w * 32 + 16) * 32]);
    __syncthreads();

    short8 af[4], bfr[4];
#pragma unroll
    for (int i = 0; i < 4; ++i)
      af[i] = *(const short8*)&As[(wm + i * 16 + l16) * 32 + quad * 8];
#pragma unroll
    for (int i = 0; i < 4; ++i)
      bfr[i] = *(const short8*)&Bs[(wn + i * 16 + l16) * 32 + quad * 8];
#pragma unroll
    for (int i = 0; i < 4; ++i)
#pragma unroll
      for (int j = 0; j < 4; ++j)
        acc[i][j] = MFMA16(af[i], bfr[j], acc[i][j]);
    __syncthreads();
  }
}

// ---------------------------------------------------------------------------
// QKV projection. grid (64, 8, 3). z==0 output pre-scaled by 0.125*log2e.
// ---------------------------------------------------------------------------
__global__ __launch_bounds__(256) void gemm_qkv(
    const float* __restrict__ qin, const float* __restrict__ kin, const float* __restrict__ vin,
    const ushort* __restrict__ Wqb, const ushort* __restrict__ Wkb, const ushort* __restrict__ Wvb,
    const float* __restrict__ bq, const float* __restrict__ bk, const float* __restrict__ bv,
    ushort* __restrict__ Qb, ushort* __restrict__ Kb, ushort* __restrict__ Vt) {
  __shared__ ushort As[128 * 32];
  __shared__ ushort Bs[128 * 32];

  const int z = blockIdx.z;
  const float*  A    = (z == 0) ? qin : (z == 1) ? kin : vin;
  const ushort* W    = (z == 0) ? Wqb : (z == 1) ? Wkb : Wvb;
  const float*  bias = (z == 0) ? bq  : (z == 1) ? bk  : bv;

  const int m0 = blockIdx.x * 128;
  const int n0 = blockIdx.y * 128;

  f32x4 acc[4][4] = {};
  gemm_core_mixed(A, W, As, Bs, m0, n0, acc);

  const int tid  = threadIdx.x;
  const int w    = tid >> 6;
  const int lane = tid & 63;
  const int quad = lane >> 4;
  const int l16  = lane & 15;
  const int wm   = (w >> 1) * 64;
  const int wn   = (w & 1) * 64;

  float bvv[4];
#pragma unroll
  for (int j = 0; j < 4; ++j) bvv[j] = bias[n0 + wn + j * 16 + l16];

  if (z < 2) {
    ushort* Out = (z == 0) ? Qb : Kb;
    const float sc = (z == 0) ? 0.1803368801f : 1.0f;  // 0.125*log2(e)
#pragma unroll
    for (int i = 0; i < 4; ++i) {
      const int m = m0 + wm + i * 16 + quad * 4;
#pragma unroll
      for (int j = 0; j < 4; ++j) {
        const int n = n0 + wn + j * 16 + l16;
#pragma unroll
        for (int r = 0; r < 4; ++r)
          Out[(size_t)(m + r) * 1024 + n] = f2bf((acc[i][j][r] + bvv[j]) * sc);
      }
    }
  } else {
#pragma unroll
    for (int i = 0; i < 4; ++i) {
      const int mrow = m0 + wm + i * 16 + quad * 4;
      const int bb   = mrow >> 11;
      const int s0   = mrow & 2047;
#pragma unroll
      for (int j = 0; j < 4; ++j) {
        const int n = n0 + wn + j * 16 + l16;        // n = h*64 + dk
        ushort4 pk;
        pk.x = f2bf(acc[i][j][0] + bvv[j]);
        pk.y = f2bf(acc[i][j][1] + bvv[j]);
        pk.z = f2bf(acc[i][j][2] + bvv[j]);
        pk.w = f2bf(acc[i][j][3] + bvv[j]);
        *(ushort4*)&Vt[(size_t)((bb * 16 + (n >> 6)) * 64 + (n & 63)) * 2048 + s0] = pk;
      }
    }
  }
}

// ---------------------------------------------------------------------------
// Flash attention v2. grid (16 qt, 64 bh), 4 waves; Q-tile 128 (wave owns 32
// q-rows as 2 groups of 16); K-tile 64. K / V^T MFMA B-fragments are loaded
// DIRECTLY from global (16B/lane, L1-resident tiles) — no LDS staging, no
// __syncthreads in the K-loop. LDS holds only the wave-private P strips.
// qt reversed so the longest blocks dispatch first. Output in place into Qb.
// ---------------------------------------------------------------------------
__global__ __launch_bounds__(256) void attn(
    ushort* __restrict__ Qb, const ushort* __restrict__ Kb,
    const ushort* __restrict__ Vt, const int* __restrict__ mask) {
  __shared__ ushort Ps[4][2][16 * 68];   // [wave][qgroup][16 x 68 padded]

  const int qt = 15 - blockIdx.x, bh = blockIdx.y;
  const int b = bh >> 4, h = bh & 15;
  const int q0 = qt * 128;
  const int tid = threadIdx.x, w = tid >> 6, lane = tid & 63;
  const int quad = lane >> 4, l16 = lane & 15;

  // Q A-fragments for both q-groups: row = q0 + w*32 + qg*16 + l16
  short8 qf[2][2];
#pragma unroll
  for (int qg = 0; qg < 2; ++qg) {
    const size_t qoff =
        (size_t)(b * 2048 + q0 + w * 32 + qg * 16 + l16) * 1024 + h * 64 + quad * 8;
    qf[qg][0] = *(const short8*)&Qb[qoff];
    qf[qg][1] = *(const short8*)&Qb[qoff + 32];
  }

  f32x4 oacc[2][4] = {};
  float lsum[2][4] = {{0.f, 0.f, 0.f, 0.f}, {0.f, 0.f, 0.f, 0.f}};

  const int rhi0 = q0 + w * 32 + 15;        // highest q-row of group 0
  const int rhi1 = rhi0 + 16;               // highest q-row of group 1
  const int nkt  = (rhi1 >> 6) + 1;         // per-wave causal tile bound

  for (int kt = 0; kt < nkt; ++kt) {
    const int k0 = kt * 64;
    const bool do0 = (k0 <= rhi0);          // wave-uniform

    // K B-fragments direct from global: B[n=key][k=dk]
    short8 kf[4][2];
#pragma unroll
    for (int nj = 0; nj < 4; ++nj) {
      const size_t ko =
          (size_t)(b * 2048 + k0 + nj * 16 + l16) * 1024 + h * 64 + quad * 8;
      kf[nj][0] = *(const short8*)&Kb[ko];
      kf[nj][1] = *(const short8*)&Kb[ko + 32];
    }
    int pm[4];
#pragma unroll
    for (int nj = 0; nj < 4; ++nj) pm[nj] = mask[b * 2048 + k0 + nj * 16 + l16];

    // scores + softmax numerators per q-group
#pragma unroll
    for (int qg = 0; qg < 2; ++qg) {
      if (qg == 0 && !do0) continue;
#pragma unroll
      for (int nj = 0; nj < 4; ++nj) {
        f32x4 z4 = {0.f, 0.f, 0.f, 0.f};
        z4 = MFMA16(qf[qg][0], kf[nj][0], z4);
        z4 = MFMA16(qf[qg][1], kf[nj][1], z4);
        const int key = k0 + nj * 16 + l16;
#pragma unroll
        for (int r = 0; r < 4; ++r) {
          const int qr = q0 + w * 32 + qg * 16 + quad * 4 + r;
          const bool ok = (pm[nj] != 0) && (key <= qr);
          const float p = __builtin_amdgcn_exp2f(ok ? z4[r] : -1e5f);
          lsum[qg][r] += p;
          Ps[w][qg][(quad * 4 + r) * 68 + nj * 16 + l16] = f2bf(p);
        }
      }
    }
    // no barrier: Ps strip is wave-private; within-wave LDS ordering suffices

    // O += P.V ; V^T B-fragments direct from global: B[n=dim][k=key]
#pragma unroll
    for (int ks = 0; ks < 2; ++ks) {
      const short8 pf1 = *(const short8*)&Ps[w][1][l16 * 68 + ks * 32 + quad * 8];
      short8 pf0 = pf1;
      if (do0) pf0 = *(const short8*)&Ps[w][0][l16 * 68 + ks * 32 + quad * 8];
#pragma unroll
      for (int nb = 0; nb < 4; ++nb) {
        const short8 vf = *(const short8*)&Vt[
            (size_t)(bh * 64 + nb * 16 + l16) * 2048 + k0 + ks * 32 + quad * 8];
        if (do0) oacc[0][nb] = MFMA16(pf0, vf, oacc[0][nb]);
        oacc[1][nb] = MFMA16(pf1, vf, oacc[1][nb]);
      }
    }
  }

  // normalize and write back in place
#pragma unroll
  for (int qg = 0; qg < 2; ++qg) {
#pragma unroll
    for (int r = 0; r < 4; ++r) {
      float v = lsum[qg][r];
      v += __shfl_xor(v, 1);
      v += __shfl_xor(v, 2);
      v += __shfl_xor(v, 4);
      v += __shfl_xor(v, 8);
      lsum[qg][r] = 1.0f / v;
    }
#pragma unroll
    for (int nb = 0; nb < 4; ++nb)
#pragma unroll
      for (int r = 0; r < 4; ++r) {
        const int qq = q0 + w * 32 + qg * 16 + quad * 4 + r;
        Qb[(size_t)(b * 2048 + qq) * 1024 + h * 64 + nb * 16 + l16] =
            f2bf(oacc[qg][nb][r] * lsum[qg][r]);
      }
  }
}

// ---------------------------------------------------------------------------
// Output projection: out = X @ Wp^T + bp, fp32 out. grid (64, 8). X == Qb.
// ---------------------------------------------------------------------------
__global__ __launch_bounds__(256) void gemm_proj(
    const ushort* __restrict__ Xin, const ushort* __restrict__ Wpb,
    const float* __restrict__ bp, float* __restrict__ Out) {
  __shared__ ushort As[128 * 32];
  __shared__ ushort Bs[128 * 32];

  const int m0 = blockIdx.x * 128;
  const int n0 = blockIdx.y * 128;

  f32x4 acc[4][4] = {};
  gemm_core_bf(Xin, Wpb, As, Bs, m0, n0, acc);

  const int tid  = threadIdx.x;
  const int w    = tid >> 6;
  const int lane = tid & 63;
  const int quad = lane >> 4;
  const int l16  = lane & 15;
  const int wm   = (w >> 1) * 64;
  const int wn   = (w & 1) * 64;

  float bvv[4];
#pragma unroll
  for (int j = 0; j < 4; ++j) bvv[j] = bp[n0 + wn + j * 16 + l16];

#pragma unroll
  for (int i = 0; i < 4; ++i) {
    const int m = m0 + wm + i * 16 + quad * 4;
#pragma unroll
    for (int j = 0; j < 4; ++j) {
      const int n = n0 + wn + j * 16 + l16;
#pragma unroll
      for (int r = 0; r < 4; ++r)
        Out[(size_t)(m + r) * 1024 + n] = acc[i][j][r] + bvv[j];
    }
  }
}

extern "C" void kernel_launch(void* const* d_in, const int* in_sizes, int n_in,
                              void* d_out, int out_size, void* d_ws, size_t ws_size,
                              hipStream_t stream) {
  const float* q    = (const float*)d_in[0];
  const float* k    = (const float*)d_in[1];
  const float* v    = (const float*)d_in[2];
  const int*   mask = (const int*)d_in[3];
  const float* Wq   = (const float*)d_in[4];
  const float* bq   = (const float*)d_in[5];
  const float* Wk   = (const float*)d_in[6];
  const float* bk   = (const float*)d_in[7];
  const float* Wv   = (const float*)d_in[8];
  const float* bv   = (const float*)d_in[9];
  const float* Wp   = (const float*)d_in[10];
  const float* bp   = (const float*)d_in[11];
  float* out = (float*)d_out;

  char* ws = (char*)d_ws;
  ushort* Qb  = (ushort*)(ws);                      // attn writes X in place
  ushort* Kb  = (ushort*)(ws + (size_t)SZB);
  ushort* Vt  = (ushort*)(ws + (size_t)2 * SZB);
  ushort* Wqb = (ushort*)(ws + (size_t)3 * SZB);
  ushort* Wkb = (ushort*)(ws + (size_t)3 * SZB + WSZ);
  ushort* Wvb = (ushort*)(ws + (size_t)3 * SZB + 2 * WSZ);
  ushort* Wpb = (ushort*)(ws + (size_t)3 * SZB + 3 * WSZ);

  dim3 blk(256);
  cvt_w<<<dim3(512, 4), blk, 0, stream>>>(Wq, Wk, Wv, Wp, Wqb, Wkb, Wvb, Wpb);
  gemm_qkv<<<dim3(64, 8, 3), blk, 0, stream>>>(q, k, v, Wqb, Wkb, Wvb,
                                               bq, bk, bv, Qb, Kb, Vt);
  attn<<<dim3(16, 64), blk, 0, stream>>>(Qb, Kb, Vt, mask);
  gemm_proj<<<dim3(64, 8), blk, 0, stream>>>(Qb, Wpb, bp, out);
}

// Round 6
// 476.593 us; speedup vs baseline: 1.1561x; 1.1561x over previous
//
#include <hip/hip_runtime.h>
#include <stdint.h>

// B=4, S=2048, D=1024, H=16, DK=64. fp32 in/out, bf16 MFMA internal.
// All hot loops use a SINGLE-barrier double-buffered LDS pipeline:
//   for kt: { barrier; stage tile kt+1 into buf[(kt+1)&1]; compute kt from
//   buf[kt&1]; }  -> every global load flies under one full compute phase
//   before the compiler's vmcnt(0) drain at the next barrier.
// Pipeline (ws = 58.7 MB):
//   0) cvt_w: weights fp32 -> bf16
//   1) gemm_qkv: Q,K -> bf16 [8192][1024] (Q pre-scaled by 0.125*log2e);
//      V -> Vt[(b,h,dk)][s]. A: fp32 regs (+2-tile prefetch) -> cvt ->
//      padded LDS; W: async global_load_lds.
//   2) attn: flash causal, Q-tile 128, K-tile 64, double-buffered padded
//      Ks/Vts, wave-private P strips (no extra barrier), in-place into Qb.
//   3) gemm_proj: pure-bf16 glds double-buffer -> fp32 d_out.

#define SZB (8192u * 1024u * 2u)
#define WSZ (1024u * 1024u * 2u)

typedef __attribute__((ext_vector_type(8))) short  short8;
typedef __attribute__((ext_vector_type(4))) float  f32x4;

#define MFMA16(a, b, c) __builtin_amdgcn_mfma_f32_16x16x32_bf16(a, b, c, 0, 0, 0)

__device__ __forceinline__ ushort f2bf(float f) {        // RNE (epilogues)
  uint32_t u = __float_as_uint(f);
  u += 0x7FFF + ((u >> 16) & 1);
  return (ushort)(u >> 16);
}
__device__ __forceinline__ ushort f2bf_fast(float f) {   // round-half-up
  return (ushort)((__float_as_uint(f) + 0x8000u) >> 16);
}
__device__ __forceinline__ short8 cvt8(float4 a, float4 b) {
  short8 r;
  r[0] = (short)f2bf_fast(a.x); r[1] = (short)f2bf_fast(a.y);
  r[2] = (short)f2bf_fast(a.z); r[3] = (short)f2bf_fast(a.w);
  r[4] = (short)f2bf_fast(b.x); r[5] = (short)f2bf_fast(b.y);
  r[6] = (short)f2bf_fast(b.z); r[7] = (short)f2bf_fast(b.w);
  return r;
}
__device__ __forceinline__ void gl_lds16(const ushort* g, ushort* l) {
  __builtin_amdgcn_global_load_lds(
      (__attribute__((address_space(1))) void*)g,
      (__attribute__((address_space(3))) void*)l, 16, 0, 0);
}

// ---------------------------------------------------------------------------
// Weight conversion: 4 x [1024][1024] fp32 -> bf16. grid (512, 4).
// ---------------------------------------------------------------------------
__global__ __launch_bounds__(256) void cvt_w(
    const float* __restrict__ Wq, const float* __restrict__ Wk,
    const float* __restrict__ Wv, const float* __restrict__ Wp,
    ushort* __restrict__ Wqb, ushort* __restrict__ Wkb,
    ushort* __restrict__ Wvb, ushort* __restrict__ Wpb) {
  const int z = blockIdx.y;
  const float* s = (z == 0) ? Wq : (z == 1) ? Wk : (z == 2) ? Wv : Wp;
  ushort* d = (z == 0) ? Wqb : (z == 1) ? Wkb : (z == 2) ? Wvb : Wpb;
  const size_t i = (size_t)(blockIdx.x * 256 + threadIdx.x) * 8;
  *(short8*)&d[i] = cvt8(*(const float4*)&s[i], *(const float4*)&s[i + 4]);
}

// ---------------------------------------------------------------------------
// Mixed core: C = A[M,K]fp32 * W[N,K]bf16^T. 128x128, BK=32, single barrier.
// As: 2 x [128][36] padded (manual cvt staging); Bs: 2 x [128][32] (glds).
// ---------------------------------------------------------------------------
__device__ __forceinline__ void gemm_core_mixed(
    const float* __restrict__ A, const ushort* __restrict__ Wb,
    ushort* As, ushort* Bs, int m0, int n0, f32x4 acc[4][4]) {
  const int tid = threadIdx.x, w = tid >> 6, lane = tid & 63;
  const int quad = lane >> 4, l16 = lane & 15;
  const int wm = (w >> 1) * 64, wn = (w & 1) * 64;
  const int r0 = tid >> 2, r1 = r0 + 64, c0 = (tid & 3) * 8;

  const ushort* Wg = Wb + (size_t)(n0 + w * 32 + (lane >> 2)) * 1024 + (lane & 3) * 8;
  const float* Ag0 = A + (size_t)(m0 + r0) * 1024 + c0;
  const float* Ag1 = A + (size_t)(m0 + r1) * 1024 + c0;

  // prologue: stage kt=0, prefetch A regs for kt=1
  float4 a0 = *(const float4*)Ag0, a1 = *(const float4*)(Ag0 + 4);
  float4 a2 = *(const float4*)Ag1, a3 = *(const float4*)(Ag1 + 4);
  *(short8*)&As[r0 * 36 + c0] = cvt8(a0, a1);
  *(short8*)&As[r1 * 36 + c0] = cvt8(a2, a3);
  gl_lds16(Wg,         &Bs[(w * 32) * 32]);
  gl_lds16(Wg + 16384, &Bs[(w * 32 + 16) * 32]);
  a0 = *(const float4*)(Ag0 + 32); a1 = *(const float4*)(Ag0 + 36);
  a2 = *(const float4*)(Ag1 + 32); a3 = *(const float4*)(Ag1 + 36);

  for (int kt = 0; kt < 32; ++kt) {
    __syncthreads();                 // buf[kt&1] staged & visible
    if (kt < 31) {                   // stage kt+1 into the other buffer
      const int nb = (kt + 1) & 1;
      *(short8*)&As[nb * 4608 + r0 * 36 + c0] = cvt8(a0, a1);
      *(short8*)&As[nb * 4608 + r1 * 36 + c0] = cvt8(a2, a3);
      const int kn = (kt + 1) * 32;
      gl_lds16(Wg + kn,         &Bs[nb * 4096 + (w * 32) * 32]);
      gl_lds16(Wg + 16384 + kn, &Bs[nb * 4096 + (w * 32 + 16) * 32]);
      if (kt < 30) {                 // A regs two tiles ahead
        const int k2 = (kt + 2) * 32;
        a0 = *(const float4*)(Ag0 + k2); a1 = *(const float4*)(Ag0 + k2 + 4);
        a2 = *(const float4*)(Ag1 + k2); a3 = *(const float4*)(Ag1 + k2 + 4);
      }
    }
    const int cb = kt & 1;
    short8 af[4], bfr[4];
#pragma unroll
    for (int i = 0; i < 4; ++i)
      af[i] = *(const short8*)&As[cb * 4608 + (wm + i * 16 + l16) * 36 + quad * 8];
#pragma unroll
    for (int i = 0; i < 4; ++i)
      bfr[i] = *(const short8*)&Bs[cb * 4096 + (wn + i * 16 + l16) * 32 + quad * 8];
#pragma unroll
    for (int i = 0; i < 4; ++i)
#pragma unroll
      for (int j = 0; j < 4; ++j)
        acc[i][j] = MFMA16(af[i], bfr[j], acc[i][j]);
  }
}

// ---------------------------------------------------------------------------
// Pure-bf16 core: glds double-buffer, single barrier. As/Bs: 2 x [128][32].
// ---------------------------------------------------------------------------
__device__ __forceinline__ void gemm_core_bf(
    const ushort* __restrict__ A, const ushort* __restrict__ Wb,
    ushort* As, ushort* Bs, int m0, int n0, f32x4 acc[4][4]) {
  const int tid = threadIdx.x, w = tid >> 6, lane = tid & 63;
  const int quad = lane >> 4, l16 = lane & 15;
  const int wm = (w >> 1) * 64, wn = (w & 1) * 64;

  const ushort* Ag = A  + (size_t)(m0 + w * 32 + (lane >> 2)) * 1024 + (lane & 3) * 8;
  const ushort* Wg = Wb + (size_t)(n0 + w * 32 + (lane >> 2)) * 1024 + (lane & 3) * 8;

  gl_lds16(Ag,         &As[(w * 32) * 32]);
  gl_lds16(Ag + 16384, &As[(w * 32 + 16) * 32]);
  gl_lds16(Wg,         &Bs[(w * 32) * 32]);
  gl_lds16(Wg + 16384, &Bs[(w * 32 + 16) * 32]);

  for (int kt = 0; kt < 32; ++kt) {
    __syncthreads();
    if (kt < 31) {
      const int nb = (kt + 1) & 1, kn = (kt + 1) * 32;
      gl_lds16(Ag + kn,         &As[nb * 4096 + (w * 32) * 32]);
      gl_lds16(Ag + 16384 + kn, &As[nb * 4096 + (w * 32 + 16) * 32]);
      gl_lds16(Wg + kn,         &Bs[nb * 4096 + (w * 32) * 32]);
      gl_lds16(Wg + 16384 + kn, &Bs[nb * 4096 + (w * 32 + 16) * 32]);
    }
    const int cb = kt & 1;
    short8 af[4], bfr[4];
#pragma unroll
    for (int i = 0; i < 4; ++i)
      af[i] = *(const short8*)&As[cb * 4096 + (wm + i * 16 + l16) * 32 + quad * 8];
#pragma unroll
    for (int i = 0; i < 4; ++i)
      bfr[i] = *(const short8*)&Bs[cb * 4096 + (wn + i * 16 + l16) * 32 + quad * 8];
#pragma unroll
    for (int i = 0; i < 4; ++i)
#pragma unroll
      for (int j = 0; j < 4; ++j)
        acc[i][j] = MFMA16(af[i], bfr[j], acc[i][j]);
  }
}

// ---------------------------------------------------------------------------
// QKV projection. grid (64, 8, 3). z==0 output pre-scaled by 0.125*log2e.
// ---------------------------------------------------------------------------
__global__ __launch_bounds__(256) void gemm_qkv(
    const float* __restrict__ qin, const float* __restrict__ kin, const float* __restrict__ vin,
    const ushort* __restrict__ Wqb, const ushort* __restrict__ Wkb, const ushort* __restrict__ Wvb,
    const float* __restrict__ bq, const float* __restrict__ bk, const float* __restrict__ bv,
    ushort* __restrict__ Qb, ushort* __restrict__ Kb, ushort* __restrict__ Vt) {
  __shared__ ushort As[2 * 128 * 36];
  __shared__ ushort Bs[2 * 128 * 32];

  const int z = blockIdx.z;
  const float*  A    = (z == 0) ? qin : (z == 1) ? kin : vin;
  const ushort* W    = (z == 0) ? Wqb : (z == 1) ? Wkb : Wvb;
  const float*  bias = (z == 0) ? bq  : (z == 1) ? bk  : bv;

  const int m0 = blockIdx.x * 128;
  const int n0 = blockIdx.y * 128;

  f32x4 acc[4][4] = {};
  gemm_core_mixed(A, W, As, Bs, m0, n0, acc);

  const int tid = threadIdx.x, w = tid >> 6, lane = tid & 63;
  const int quad = lane >> 4, l16 = lane & 15;
  const int wm = (w >> 1) * 64, wn = (w & 1) * 64;

  float bvv[4];
#pragma unroll
  for (int j = 0; j < 4; ++j) bvv[j] = bias[n0 + wn + j * 16 + l16];

  if (z < 2) {
    ushort* Out = (z == 0) ? Qb : Kb;
    const float sc = (z == 0) ? 0.1803368801f : 1.0f;  // 0.125*log2(e)
#pragma unroll
    for (int i = 0; i < 4; ++i) {
      const int m = m0 + wm + i * 16 + quad * 4;
#pragma unroll
      for (int j = 0; j < 4; ++j) {
        const int n = n0 + wn + j * 16 + l16;
#pragma unroll
        for (int r = 0; r < 4; ++r)
          Out[(size_t)(m + r) * 1024 + n] = f2bf((acc[i][j][r] + bvv[j]) * sc);
      }
    }
  } else {
#pragma unroll
    for (int i = 0; i < 4; ++i) {
      const int mrow = m0 + wm + i * 16 + quad * 4;
      const int bb = mrow >> 11, s0 = mrow & 2047;
#pragma unroll
      for (int j = 0; j < 4; ++j) {
        const int n = n0 + wn + j * 16 + l16;        // n = h*64 + dk
        ushort4 pk;
        pk.x = f2bf(acc[i][j][0] + bvv[j]);
        pk.y = f2bf(acc[i][j][1] + bvv[j]);
        pk.z = f2bf(acc[i][j][2] + bvv[j]);
        pk.w = f2bf(acc[i][j][3] + bvv[j]);
        *(ushort4*)&Vt[(size_t)((bb * 16 + (n >> 6)) * 64 + (n & 63)) * 2048 + s0] = pk;
      }
    }
  }
}

// ---------------------------------------------------------------------------
// Flash attention v3. grid (16 qt, 64 bh), 4 waves. Q-tile 128 (wave owns 32
// q-rows as 2 groups of 16), K-tile 64. Double-buffered padded Ks/Vts,
// single barrier per kt; Ps strips wave-private. Output in place into Qb.
// ---------------------------------------------------------------------------
__global__ __launch_bounds__(256) void attn(
    ushort* __restrict__ Qb, const ushort* __restrict__ Kb,
    const ushort* __restrict__ Vt, const int* __restrict__ mask) {
  __shared__ ushort Ks[2][64 * 68];      // [key][dk] padded
  __shared__ ushort Vts[2][64 * 68];     // [dk][key] padded
  __shared__ ushort Ps[4][2][16 * 68];   // [wave][qgroup] padded

  const int qt = 15 - blockIdx.x, bh = blockIdx.y;
  const int b = bh >> 4, h = bh & 15;
  const int q0 = qt * 128;
  const int tid = threadIdx.x, w = tid >> 6, lane = tid & 63;
  const int quad = lane >> 4, l16 = lane & 15;

  short8 qf[2][2];
#pragma unroll
  for (int qg = 0; qg < 2; ++qg) {
    const size_t qoff =
        (size_t)(b * 2048 + q0 + w * 32 + qg * 16 + l16) * 1024 + h * 64 + quad * 8;
    qf[qg][0] = *(const short8*)&Qb[qoff];
    qf[qg][1] = *(const short8*)&Qb[qoff + 32];
  }

  f32x4 oacc[2][4] = {};
  float lsum[2][4] = {{0.f, 0.f, 0.f, 0.f}, {0.f, 0.f, 0.f, 0.f}};

  const int nkt  = 2 * qt + 2;
  const int qlo0 = q0 + w * 32, qlo1 = qlo0 + 16;
  const int rhi0 = qlo0 + 15,   rhi1 = qlo1 + 15;

  // staging map: thread covers rows sr0/sr1 (8 chunks of 16B per 128B row)
  const int sr0 = tid >> 3, sr1 = sr0 + 32, scol = (tid & 7) * 8;
  short8 kr0, kr1, vr0, vr1;
#define LOADKV(K0)                                                            \
  kr0 = *(const short8*)&Kb[(size_t)(b * 2048 + (K0) + sr0) * 1024 + h * 64 + scol]; \
  kr1 = *(const short8*)&Kb[(size_t)(b * 2048 + (K0) + sr1) * 1024 + h * 64 + scol]; \
  vr0 = *(const short8*)&Vt[(size_t)(bh * 64 + sr0) * 2048 + (K0) + scol];    \
  vr1 = *(const short8*)&Vt[(size_t)(bh * 64 + sr1) * 2048 + (K0) + scol];
#define WRITEKV(BUF)                                                          \
  *(short8*)&Ks[BUF][sr0 * 68 + scol]  = kr0;                                 \
  *(short8*)&Ks[BUF][sr1 * 68 + scol]  = kr1;                                 \
  *(short8*)&Vts[BUF][sr0 * 68 + scol] = vr0;                                 \
  *(short8*)&Vts[BUF][sr1 * 68 + scol] = vr1;

  LOADKV(0)
  WRITEKV(0)
  if (nkt > 1) { LOADKV(64) }

  for (int kt = 0; kt < nkt; ++kt) {
    const int k0 = kt * 64, cb = kt & 1;
    __syncthreads();                 // buf[cb] staged & visible
    if (kt + 1 < nkt) {
      WRITEKV((kt + 1) & 1)
      if (kt + 2 < nkt) { LOADKV((kt + 2) * 64) }
    }
    int pm[4];
#pragma unroll
    for (int nj = 0; nj < 4; ++nj) pm[nj] = mask[b * 2048 + k0 + nj * 16 + l16];

    const bool d0 = (k0 <= rhi0), d1 = (k0 <= rhi1);

    // QK^T + softmax numerators (K frags shared across both q-groups)
#pragma unroll
    for (int nj = 0; nj < 4; ++nj) {
      const short8 kf0 = *(const short8*)&Ks[cb][(nj * 16 + l16) * 68 + quad * 8];
      const short8 kf1 = *(const short8*)&Ks[cb][(nj * 16 + l16) * 68 + 32 + quad * 8];
      const int key = k0 + nj * 16 + l16;
      if (d0) {
        f32x4 z = {0.f, 0.f, 0.f, 0.f};
        z = MFMA16(qf[0][0], kf0, z);
        z = MFMA16(qf[0][1], kf1, z);
#pragma unroll
        for (int r = 0; r < 4; ++r) {
          const int qr = qlo0 + quad * 4 + r;
          const bool ok = (pm[nj] != 0) && (key <= qr);
          const float p = __builtin_amdgcn_exp2f(ok ? z[r] : -1e5f);
          lsum[0][r] += p;
          Ps[w][0][(quad * 4 + r) * 68 + nj * 16 + l16] = f2bf(p);
        }
      }
      if (d1) {
        f32x4 z = {0.f, 0.f, 0.f, 0.f};
        z = MFMA16(qf[1][0], kf0, z);
        z = MFMA16(qf[1][1], kf1, z);
#pragma unroll
        for (int r = 0; r < 4; ++r) {
          const int qr = qlo1 + quad * 4 + r;
          const bool ok = (pm[nj] != 0) && (key <= qr);
          const float p = __builtin_amdgcn_exp2f(ok ? z[r] : -1e5f);
          lsum[1][r] += p;
          Ps[w][1][(quad * 4 + r) * 68 + nj * 16 + l16] = f2bf(p);
        }
      }
    }
    // no barrier: Ps strip wave-private; lgkmcnt orders the round trip

    // O += P.V (V frags shared across both q-groups)
#pragma unroll
    for (int ks = 0; ks < 2; ++ks) {
      short8 pf0 = {}, pf1 = {};
      if (d0) pf0 = *(const short8*)&Ps[w][0][l16 * 68 + ks * 32 + quad * 8];
      if (d1) pf1 = *(const short8*)&Ps[w][1][l16 * 68 + ks * 32 + quad * 8];
#pragma unroll
      for (int nb = 0; nb < 4; ++nb) {
        const short8 vf =
            *(const short8*)&Vts[cb][(nb * 16 + l16) * 68 + ks * 32 + quad * 8];
        if (d0) oacc[0][nb] = MFMA16(pf0, vf, oacc[0][nb]);
        if (d1) oacc[1][nb] = MFMA16(pf1, vf, oacc[1][nb]);
      }
    }
  }

  // normalize and write back in place
#pragma unroll
  for (int qg = 0; qg < 2; ++qg) {
#pragma unroll
    for (int r = 0; r < 4; ++r) {
      float v = lsum[qg][r];
      v += __shfl_xor(v, 1);
      v += __shfl_xor(v, 2);
      v += __shfl_xor(v, 4);
      v += __shfl_xor(v, 8);
      lsum[qg][r] = 1.0f / v;
    }
    const int qlo = (qg == 0) ? qlo0 : qlo1;
#pragma unroll
    for (int nb = 0; nb < 4; ++nb)
#pragma unroll
      for (int r = 0; r < 4; ++r) {
        const int qq = qlo + quad * 4 + r;
        Qb[(size_t)(b * 2048 + qq) * 1024 + h * 64 + nb * 16 + l16] =
            f2bf(oacc[qg][nb][r] * lsum[qg][r]);
      }
  }
}

// ---------------------------------------------------------------------------
// Output projection: out = X @ Wp^T + bp, fp32 out. grid (64, 8). X == Qb.
// ---------------------------------------------------------------------------
__global__ __launch_bounds__(256) void gemm_proj(
    const ushort* __restrict__ Xin, const ushort* __restrict__ Wpb,
    const float* __restrict__ bp, float* __restrict__ Out) {
  __shared__ ushort As[2 * 128 * 32];
  __shared__ ushort Bs[2 * 128 * 32];

  const int m0 = blockIdx.x * 128;
  const int n0 = blockIdx.y * 128;

  f32x4 acc[4][4] = {};
  gemm_core_bf(Xin, Wpb, As, Bs, m0, n0, acc);

  const int tid = threadIdx.x, w = tid >> 6, lane = tid & 63;
  const int quad = lane >> 4, l16 = lane & 15;
  const int wm = (w >> 1) * 64, wn = (w & 1) * 64;

  float bvv[4];
#pragma unroll
  for (int j = 0; j < 4; ++j) bvv[j] = bp[n0 + wn + j * 16 + l16];

#pragma unroll
  for (int i = 0; i < 4; ++i) {
    const int m = m0 + wm + i * 16 + quad * 4;
#pragma unroll
    for (int j = 0; j < 4; ++j) {
      const int n = n0 + wn + j * 16 + l16;
#pragma unroll
      for (int r = 0; r < 4; ++r)
        Out[(size_t)(m + r) * 1024 + n] = acc[i][j][r] + bvv[j];
    }
  }
}

extern "C" void kernel_launch(void* const* d_in, const int* in_sizes, int n_in,
                              void* d_out, int out_size, void* d_ws, size_t ws_size,
                              hipStream_t stream) {
  const float* q    = (const float*)d_in[0];
  const float* k    = (const float*)d_in[1];
  const float* v    = (const float*)d_in[2];
  const int*   mask = (const int*)d_in[3];
  const float* Wq   = (const float*)d_in[4];
  const float* bq   = (const float*)d_in[5];
  const float* Wk   = (const float*)d_in[6];
  const float* bk   = (const float*)d_in[7];
  const float* Wv   = (const float*)d_in[8];
  const float* bv   = (const float*)d_in[9];
  const float* Wp   = (const float*)d_in[10];
  const float* bp   = (const float*)d_in[11];
  float* out = (float*)d_out;

  char* ws = (char*)d_ws;
  ushort* Qb  = (ushort*)(ws);                      // attn writes X in place
  ushort* Kb  = (ushort*)(ws + (size_t)SZB);
  ushort* Vt  = (ushort*)(ws + (size_t)2 * SZB);
  ushort* Wqb = (ushort*)(ws + (size_t)3 * SZB);
  ushort* Wkb = (ushort*)(ws + (size_t)3 * SZB + WSZ);
  ushort* Wvb = (ushort*)(ws + (size_t)3 * SZB + 2 * WSZ);
  ushort* Wpb = (ushort*)(ws + (size_t)3 * SZB + 3 * WSZ);

  dim3 blk(256);
  cvt_w<<<dim3(512, 4), blk, 0, stream>>>(Wq, Wk, Wv, Wp, Wqb, Wkb, Wvb, Wpb);
  gemm_qkv<<<dim3(64, 8, 3), blk, 0, stream>>>(q, k, v, Wqb, Wkb, Wvb,
                                               bq, bk, bv, Qb, Kb, Vt);
  attn<<<dim3(16, 64), blk, 0, stream>>>(Qb, Kb, Vt, mask);
  gemm_proj<<<dim3(64, 8), blk, 0, stream>>>(Qb, Wpb, bp, out);
}